// Round 2
// baseline (130.451 us; speedup 1.0000x reference)
//
#include <hip/hip_runtime.h>

static constexpr int N_AGENTS = 64;   // = wave size; one lane per agent/edge
static constexpr int H_DIM    = 8;

__device__ __forceinline__ float fast_exp2(float v) {
#if __has_builtin(__builtin_amdgcn_exp2f)
    return __builtin_amdgcn_exp2f(v);   // v_exp_f32
#else
    return exp2f(v);
#endif
}

__device__ __forceinline__ float fast_rcp(float v) {
#if __has_builtin(__builtin_amdgcn_rcpf)
    return __builtin_amdgcn_rcpf(v);    // v_rcp_f32
#else
    return 1.0f / v;
#endif
}

// tanh(v) = 1 - 2/(e^{2v}+1); hw exp2/rcp are ~1 ulp, total abs err ~1e-6
__device__ __forceinline__ float fast_tanh(float v) {
    float z = fast_exp2(v * 2.8853900817779268f);  // e^{2v} = 2^(2*log2(e)*v)
    float r = fast_rcp(z + 1.0f);
    return __builtin_fmaf(-2.0f, r, 1.0f);
}

__global__ __launch_bounds__(256) void networked_ode_kernel(
    const float* __restrict__ x,    // [B, N] f32
    const float* __restrict__ W1,   // [N, H]
    const float* __restrict__ b1,   // [N, H]
    const float* __restrict__ W2,   // [N, H]
    const float* __restrict__ b2,   // [N]
    const float* __restrict__ Wc1,  // [2, H]
    const float* __restrict__ bc1,  // [H]
    const float* __restrict__ Wc2,  // [H]
    const float* __restrict__ bc2,  // [1]
    const int* __restrict__ send_idx,  // [N]
    const int* __restrict__ recv_idx,  // [N]
    float* __restrict__ out,        // [B, N] f32
    int B)
{
    const int lane           = threadIdx.x & 63;
    const int wave_in_block  = threadIdx.x >> 6;
    const int waves_per_blk  = blockDim.x >> 6;
    const int gwave          = blockIdx.x * waves_per_blk + wave_in_block;
    const int total_waves    = gridDim.x * waves_per_blk;

    // ---- per-lane (agent) intrinsic weights -> registers, amortized over rows
    float w1[H_DIM], bb1[H_DIM], w2[H_DIM];
#pragma unroll
    for (int h = 0; h < H_DIM; ++h) {
        w1[h]  = W1[lane * H_DIM + h];
        bb1[h] = b1[lane * H_DIM + h];
        w2[h]  = W2[lane * H_DIM + h];
    }
    const float b2v = b2[lane];

    // ---- wave-uniform coupling weights (compiler -> SGPRs)
    float wcs[H_DIM], wcr[H_DIM], bc1v[H_DIM], wc2v[H_DIM];
#pragma unroll
    for (int h = 0; h < H_DIM; ++h) {
        wcs[h]  = Wc1[h];          // Wc1[0][h] (x_send weight)
        wcr[h]  = Wc1[H_DIM + h];  // Wc1[1][h] (x_recv weight)
        bc1v[h] = bc1[h];
        wc2v[h] = Wc2[h];
    }
    const float bc2v = bc2[0];

    // ---- edge endpoints for edge e = lane
    const int sidx = send_idx[lane];
    const int ridx = recv_idx[lane];

    // ---- scatter-add becomes gather via inverse permutation (computed once)
    __shared__ int inv_r_s[256], inv_s_s[256];
    const int base = wave_in_block * 64;
    inv_r_s[base + ridx] = lane;
    inv_s_s[base + sidx] = lane;
    __syncthreads();
    const int inv_r = inv_r_s[base + lane];  // edge whose recv == my agent
    const int inv_s = inv_s_s[base + lane];  // edge whose send == my agent

    // ---- grid-stride over batch rows; one wave per row
    for (int row = gwave; row < B; row += total_waves) {
        const float xv = x[(size_t)row * N_AGENTS + lane];
        const float xs = __shfl(xv, sidx, 64);
        const float xr = __shfl(xv, ridx, 64);

        // coupling MLP for edge = lane
        float c = bc2v;
#pragma unroll
        for (int h = 0; h < H_DIM; ++h) {
            float a = __builtin_fmaf(xs, wcs[h], __builtin_fmaf(xr, wcr[h], bc1v[h]));
            c = __builtin_fmaf(fast_tanh(a), wc2v[h], c);
        }

        // intrinsic MLP for agent = lane
        float acc = b2v;
#pragma unroll
        for (int h = 0; h < H_DIM; ++h) {
            float a = __builtin_fmaf(xv, w1[h], bb1[h]);
            acc = __builtin_fmaf(fast_tanh(a), w2[h], acc);
        }

        // symmetric scatter: +contrib at receiver, -contrib at sender
        const float cr = __shfl(c, inv_r, 64);
        const float cs = __shfl(c, inv_s, 64);

        out[(size_t)row * N_AGENTS + lane] = acc + cr - cs;
    }
}

extern "C" void kernel_launch(void* const* d_in, const int* in_sizes, int n_in,
                              void* d_out, int out_size, void* d_ws, size_t ws_size,
                              hipStream_t stream) {
    const float* x   = (const float*)d_in[0];
    const float* W1  = (const float*)d_in[1];
    const float* b1  = (const float*)d_in[2];
    const float* W2  = (const float*)d_in[3];
    const float* b2  = (const float*)d_in[4];
    const float* Wc1 = (const float*)d_in[5];
    const float* bc1 = (const float*)d_in[6];
    const float* Wc2 = (const float*)d_in[7];
    const float* bc2 = (const float*)d_in[8];
    const int* send_idx = (const int*)d_in[9];
    const int* recv_idx = (const int*)d_in[10];

    const int B = in_sizes[0] / N_AGENTS;   // 131072

    // 2048 blocks x 4 waves = 8192 waves -> 16 rows/wave; weights amortized
    const int blocks = 2048;
    networked_ode_kernel<<<blocks, dim3(256), 0, stream>>>(
        x, W1, b1, W2, b2, Wc1, bc1, Wc2, bc2, send_idx, recv_idx,
        (float*)d_out, B);
}

// Round 3
// 123.544 us; speedup vs baseline: 1.0559x; 1.0559x over previous
//
#include <hip/hip_runtime.h>

static constexpr int N_AGENTS = 64;   // = wave size; one lane per agent/edge
static constexpr int H_DIM    = 8;

__device__ __forceinline__ float fast_exp2(float v) {
#if __has_builtin(__builtin_amdgcn_exp2f)
    return __builtin_amdgcn_exp2f(v);   // v_exp_f32
#else
    return exp2f(v);
#endif
}

__device__ __forceinline__ float fast_rcp(float v) {
#if __has_builtin(__builtin_amdgcn_rcpf)
    return __builtin_amdgcn_rcpf(v);    // v_rcp_f32
#else
    return 1.0f / v;
#endif
}

// tanh folded into consumer:
//   tanh(a) = 1 - 2*r,  r = 1/(1 + e^{2a}) = rcp(exp2(K*a) + 1),  K = 2*log2(e)
//   acc += tanh(a)*w  ==>  acc0 = base + sum(w);  acc = fma(r, -2w, acc)
// K is pre-folded into the first-layer weights/biases at setup.

__global__ __launch_bounds__(256) void networked_ode_kernel(
    const float* __restrict__ x,    // [B, N] f32
    const float* __restrict__ W1,   // [N, H]
    const float* __restrict__ b1,   // [N, H]
    const float* __restrict__ W2,   // [N, H]
    const float* __restrict__ b2,   // [N]
    const float* __restrict__ Wc1,  // [2, H]
    const float* __restrict__ bc1,  // [H]
    const float* __restrict__ Wc2,  // [H]
    const float* __restrict__ bc2,  // [1]
    const int* __restrict__ send_idx,  // [N]
    const int* __restrict__ recv_idx,  // [N]
    float* __restrict__ out,        // [B, N] f32
    int B)
{
    const int lane           = threadIdx.x & 63;
    const int wave_in_block  = threadIdx.x >> 6;
    const int waves_per_blk  = blockDim.x >> 6;
    const int gwave          = blockIdx.x * waves_per_blk + wave_in_block;
    const int total_waves    = gridDim.x * waves_per_blk;

    const float K = 2.8853900817779268f;  // 2*log2(e)

    // ---- per-lane (agent) intrinsic weights, prescaled + consumer-folded
    float w1s[H_DIM], b1s[H_DIM], m2w2[H_DIM];
    float acc0 = b2[lane];
#pragma unroll
    for (int h = 0; h < H_DIM; ++h) {
        w1s[h] = W1[lane * H_DIM + h] * K;
        b1s[h] = b1[lane * H_DIM + h] * K;
        const float w2v = W2[lane * H_DIM + h];
        m2w2[h] = -2.0f * w2v;
        acc0 += w2v;                      // tanh = 1 - 2r : the "+1*w" part
    }

    // ---- wave-uniform coupling weights (same treatment)
    float wcss[H_DIM], wcrs[H_DIM], bc1s[H_DIM], m2wc2[H_DIM];
    float c0 = bc2[0];
#pragma unroll
    for (int h = 0; h < H_DIM; ++h) {
        wcss[h] = Wc1[h] * K;             // Wc1[0][h] (x_send)
        wcrs[h] = Wc1[H_DIM + h] * K;     // Wc1[1][h] (x_recv)
        bc1s[h] = bc1[h] * K;
        const float wc2v = Wc2[h];
        m2wc2[h] = -2.0f * wc2v;
        c0 += wc2v;
    }

    // ---- edge endpoints for edge e = lane
    const int sidx = send_idx[lane];
    const int ridx = recv_idx[lane];

    // ---- scatter-add becomes gather via inverse permutation (computed once)
    __shared__ int inv_r_s[256], inv_s_s[256];
    const int base = wave_in_block * 64;
    inv_r_s[base + ridx] = lane;
    inv_s_s[base + sidx] = lane;
    __syncthreads();
    const int inv_r = inv_r_s[base + lane];  // edge whose recv == my agent
    const int inv_s = inv_s_s[base + lane];  // edge whose send == my agent

    // ---- grid-stride, 2 rows per iteration for ILP across trans chains
    for (int row0 = gwave * 2; row0 < B; row0 += total_waves * 2) {
        const bool has1 = (row0 + 1) < B;

        float xv[2];
        xv[0] = x[(size_t)row0 * N_AGENTS + lane];
        xv[1] = has1 ? x[(size_t)(row0 + 1) * N_AGENTS + lane] : 0.0f;

        float xs[2], xr[2];
#pragma unroll
        for (int r = 0; r < 2; ++r) {
            xs[r] = __shfl(xv[r], sidx, 64);
            xr[r] = __shfl(xv[r], ridx, 64);
        }

        float c[2]   = {c0, c0};
        float acc[2] = {acc0, acc0};

        // coupling MLP (edge = lane), 2 rows interleaved
#pragma unroll
        for (int h = 0; h < H_DIM; ++h) {
#pragma unroll
            for (int r = 0; r < 2; ++r) {
                const float a  = __builtin_fmaf(xs[r], wcss[h],
                                 __builtin_fmaf(xr[r], wcrs[h], bc1s[h]));
                const float rr = fast_rcp(fast_exp2(a) + 1.0f);
                c[r] = __builtin_fmaf(rr, m2wc2[h], c[r]);
            }
        }

        // intrinsic MLP (agent = lane), 2 rows interleaved
#pragma unroll
        for (int h = 0; h < H_DIM; ++h) {
#pragma unroll
            for (int r = 0; r < 2; ++r) {
                const float a  = __builtin_fmaf(xv[r], w1s[h], b1s[h]);
                const float rr = fast_rcp(fast_exp2(a) + 1.0f);
                acc[r] = __builtin_fmaf(rr, m2w2[h], acc[r]);
            }
        }

        // symmetric scatter: +contrib at receiver, -contrib at sender
#pragma unroll
        for (int r = 0; r < 2; ++r) {
            const float cr = __shfl(c[r], inv_r, 64);
            const float cs = __shfl(c[r], inv_s, 64);
            const float res = acc[r] + cr - cs;
            if (r == 0 || has1)
                out[(size_t)(row0 + r) * N_AGENTS + lane] = res;
        }
    }
}

extern "C" void kernel_launch(void* const* d_in, const int* in_sizes, int n_in,
                              void* d_out, int out_size, void* d_ws, size_t ws_size,
                              hipStream_t stream) {
    const float* x   = (const float*)d_in[0];
    const float* W1  = (const float*)d_in[1];
    const float* b1  = (const float*)d_in[2];
    const float* W2  = (const float*)d_in[3];
    const float* b2  = (const float*)d_in[4];
    const float* Wc1 = (const float*)d_in[5];
    const float* bc1 = (const float*)d_in[6];
    const float* Wc2 = (const float*)d_in[7];
    const float* bc2 = (const float*)d_in[8];
    const int* send_idx = (const int*)d_in[9];
    const int* recv_idx = (const int*)d_in[10];

    const int B = in_sizes[0] / N_AGENTS;   // 131072

    // 2048 blocks x 4 waves = 8192 waves; 2-row iters -> 8 iters/wave
    const int blocks = 2048;
    networked_ode_kernel<<<blocks, dim3(256), 0, stream>>>(
        x, W1, b1, W2, b2, Wc1, bc1, Wc2, bc2, send_idx, recv_idx,
        (float*)d_out, B);
}

// Round 4
// 121.308 us; speedup vs baseline: 1.0754x; 1.0184x over previous
//
#include <hip/hip_runtime.h>

typedef float v2f __attribute__((ext_vector_type(2)));

static constexpr int N_AGENTS = 64;   // = wave size; one lane per agent/edge
static constexpr int H_DIM    = 8;
static constexpr int ROWS     = 4;    // rows per wave-iteration (2x v2f packed)

__device__ __forceinline__ float fast_exp2(float v) {
#if __has_builtin(__builtin_amdgcn_exp2f)
    return __builtin_amdgcn_exp2f(v);   // v_exp_f32
#else
    return exp2f(v);
#endif
}

__device__ __forceinline__ float fast_rcp(float v) {
#if __has_builtin(__builtin_amdgcn_rcpf)
    return __builtin_amdgcn_rcpf(v);    // v_rcp_f32
#else
    return 1.0f / v;
#endif
}

__device__ __forceinline__ v2f fma2(v2f a, v2f b, v2f c) {
    return __builtin_elementwise_fma(a, b, c);   // -> v_pk_fma_f32
}
__device__ __forceinline__ v2f splat(float s) { return (v2f){s, s}; }

// tanh folded into consumer:
//   tanh(a) = 1 - 2*r,  r = rcp(exp2(K*a) + 1),  K = 2*log2(e) pre-folded into
//   first-layer weights; consumer acc += tanh*w  ==>  acc0 = base + sum(w),
//   acc = fma(r, -2w, acc).

__global__ __launch_bounds__(256) void networked_ode_kernel(
    const float* __restrict__ x,    // [B, N] f32
    const float* __restrict__ W1,   // [N, H]
    const float* __restrict__ b1,   // [N, H]
    const float* __restrict__ W2,   // [N, H]
    const float* __restrict__ b2,   // [N]
    const float* __restrict__ Wc1,  // [2, H]
    const float* __restrict__ bc1,  // [H]
    const float* __restrict__ Wc2,  // [H]
    const float* __restrict__ bc2,  // [1]
    const int* __restrict__ send_idx,  // [N]
    const int* __restrict__ recv_idx,  // [N]
    float* __restrict__ out,        // [B, N] f32
    int B)
{
    const int lane           = threadIdx.x & 63;
    const int wave_in_block  = threadIdx.x >> 6;
    const int waves_per_blk  = blockDim.x >> 6;
    const int gwave          = blockIdx.x * waves_per_blk + wave_in_block;
    const int total_waves    = gridDim.x * waves_per_blk;

    const float K = 2.8853900817779268f;  // 2*log2(e)

    // ---- per-lane (agent) intrinsic weights, prescaled + consumer-folded
    float w1s[H_DIM], b1s[H_DIM], m2w2[H_DIM];
    float acc0 = b2[lane];
#pragma unroll
    for (int h = 0; h < H_DIM; ++h) {
        w1s[h] = W1[lane * H_DIM + h] * K;
        b1s[h] = b1[lane * H_DIM + h] * K;
        const float w2v = W2[lane * H_DIM + h];
        m2w2[h] = -2.0f * w2v;
        acc0 += w2v;
    }

    // ---- wave-uniform coupling weights (compiler -> SGPRs)
    float wcss[H_DIM], wcrs[H_DIM], bc1s[H_DIM], m2wc2[H_DIM];
    float c0 = bc2[0];
#pragma unroll
    for (int h = 0; h < H_DIM; ++h) {
        wcss[h] = Wc1[h] * K;             // Wc1[0][h] (x_send)
        wcrs[h] = Wc1[H_DIM + h] * K;     // Wc1[1][h] (x_recv)
        bc1s[h] = bc1[h] * K;
        const float wc2v = Wc2[h];
        m2wc2[h] = -2.0f * wc2v;
        c0 += wc2v;
    }

    // ---- edge endpoints for edge e = lane
    const int sidx = send_idx[lane];
    const int ridx = recv_idx[lane];

    // ring topology in practice: send == identity permutation. Detect it
    // wave-uniformly so we can skip 2 of the 4 shuffles per row (generic
    // fallback keeps correctness for any permutation).
    const bool send_is_id = (__ballot(sidx == lane) == ~0ull);

    // ---- scatter-add becomes gather via inverse permutation (computed once)
    __shared__ int inv_r_s[256], inv_s_s[256];
    const int base = wave_in_block * 64;
    inv_r_s[base + ridx] = lane;
    inv_s_s[base + sidx] = lane;
    __syncthreads();
    const int inv_r = inv_r_s[base + lane];  // edge whose recv == my agent
    const int inv_s = inv_s_s[base + lane];  // edge whose send == my agent

    // ---- grid-stride, 4 rows per iteration (2x v2f) for ILP + packed math
    for (int row0 = gwave * ROWS; row0 < B; row0 += total_waves * ROWS) {
        float xv[ROWS], xs[ROWS], xr[ROWS];
#pragma unroll
        for (int k = 0; k < ROWS; ++k) {
            const int row = row0 + k;
            xv[k] = (row < B) ? x[(size_t)row * N_AGENTS + lane] : 0.0f;
        }
#pragma unroll
        for (int k = 0; k < ROWS; ++k) xr[k] = __shfl(xv[k], ridx, 64);
        if (send_is_id) {
#pragma unroll
            for (int k = 0; k < ROWS; ++k) xs[k] = xv[k];
        } else {
#pragma unroll
            for (int k = 0; k < ROWS; ++k) xs[k] = __shfl(xv[k], sidx, 64);
        }

        v2f XV[2] = {{xv[0], xv[1]}, {xv[2], xv[3]}};
        v2f XS[2] = {{xs[0], xs[1]}, {xs[2], xs[3]}};
        v2f XR[2] = {{xr[0], xr[1]}, {xr[2], xr[3]}};
        v2f C[2]  = {splat(c0), splat(c0)};
        v2f A[2]  = {splat(acc0), splat(acc0)};
        const v2f one = splat(1.0f);

        // coupling MLP (edge = lane), 4 rows via 2 packed lanes
#pragma unroll
        for (int h = 0; h < H_DIM; ++h) {
            const v2f wcs_ = splat(wcss[h]), wcr_ = splat(wcrs[h]);
            const v2f bcs_ = splat(bc1s[h]), mwc_ = splat(m2wc2[h]);
#pragma unroll
            for (int p = 0; p < 2; ++p) {
                v2f a = fma2(XR[p], wcr_, bcs_);
                a = fma2(XS[p], wcs_, a);
                v2f z; z.x = fast_exp2(a.x); z.y = fast_exp2(a.y);
                z = z + one;
                v2f r; r.x = fast_rcp(z.x); r.y = fast_rcp(z.y);
                C[p] = fma2(r, mwc_, C[p]);
            }
        }

        // intrinsic MLP (agent = lane)
#pragma unroll
        for (int h = 0; h < H_DIM; ++h) {
            const v2f w1_ = splat(w1s[h]), b1_ = splat(b1s[h]);
            const v2f mw2_ = splat(m2w2[h]);
#pragma unroll
            for (int p = 0; p < 2; ++p) {
                v2f a = fma2(XV[p], w1_, b1_);
                v2f z; z.x = fast_exp2(a.x); z.y = fast_exp2(a.y);
                z = z + one;
                v2f r; r.x = fast_rcp(z.x); r.y = fast_rcp(z.y);
                A[p] = fma2(r, mw2_, A[p]);
            }
        }

        // symmetric scatter: +contrib at receiver, -contrib at sender
        const float cv[ROWS] = {C[0].x, C[0].y, C[1].x, C[1].y};
        const float av[ROWS] = {A[0].x, A[0].y, A[1].x, A[1].y};
#pragma unroll
        for (int k = 0; k < ROWS; ++k) {
            const float cr = __shfl(cv[k], inv_r, 64);
            const float cs = send_is_id ? cv[k] : __shfl(cv[k], inv_s, 64);
            const int row = row0 + k;
            if (row < B)
                out[(size_t)row * N_AGENTS + lane] = av[k] + cr - cs;
        }
    }
}

extern "C" void kernel_launch(void* const* d_in, const int* in_sizes, int n_in,
                              void* d_out, int out_size, void* d_ws, size_t ws_size,
                              hipStream_t stream) {
    const float* x   = (const float*)d_in[0];
    const float* W1  = (const float*)d_in[1];
    const float* b1  = (const float*)d_in[2];
    const float* W2  = (const float*)d_in[3];
    const float* b2  = (const float*)d_in[4];
    const float* Wc1 = (const float*)d_in[5];
    const float* bc1 = (const float*)d_in[6];
    const float* Wc2 = (const float*)d_in[7];
    const float* bc2 = (const float*)d_in[8];
    const int* send_idx = (const int*)d_in[9];
    const int* recv_idx = (const int*)d_in[10];

    const int B = in_sizes[0] / N_AGENTS;   // 131072

    // 2048 blocks x 4 waves = 8192 waves = 32 waves/CU; 4 rows/iter -> 4 iters
    const int blocks = 2048;
    networked_ode_kernel<<<blocks, dim3(256), 0, stream>>>(
        x, W1, b1, W2, b2, Wc1, bc1, Wc2, bc2, send_idx, recv_idx,
        (float*)d_out, B);
}